// Round 1
// baseline (173.497 us; speedup 1.0000x reference)
//
#include <hip/hip_runtime.h>
#include <math.h>

#define BB   1024
#define MM   32
#define HH   2
#define DD   64
#define NREL 32
#define TBB  32          // b-tile per block in kernel A

// ---------------- Kernel A: Q[b][r][j] = sum_i item[b][i] * R[r][i][j] -----
// grid = (BB/TBB, NREL), block = 256.  ~2 us, near compute floor. UNCHANGED.
__global__ __launch_bounds__(256) void compute_q(
    const int* __restrict__ edge_index,     // (B,2)
    const float* __restrict__ entity_emb,   // (N_ENT, D)
    const float* __restrict__ relation_emb, // (NREL, D*D)
    float* __restrict__ qout)               // (B, NREL, D)
{
    __shared__ float R_s[DD * DD];          // 16 KB, row-major R[i][j]
    __shared__ float item_s[TBB * 68];      // stride 68: 16B-aligned, banks spread

    const int r   = blockIdx.y;
    const int b0  = blockIdx.x * TBB;
    const int tid = threadIdx.x;

    // stage R_r: 1024 float4, 4 per thread (coalesced)
    const float4* Rg = (const float4*)(relation_emb + (size_t)r * DD * DD);
    #pragma unroll
    for (int k = 0; k < 4; ++k)
        ((float4*)R_s)[tid + 256 * k] = Rg[tid + 256 * k];

    // stage 32 item rows: 512 float4, 2 per thread
    #pragma unroll
    for (int k = 0; k < 2; ++k) {
        int idx = tid + 256 * k;            // 0..511
        int bl  = idx >> 4;                 // 0..31
        int c4  = idx & 15;                 // 0..15
        int ei  = edge_index[2 * (b0 + bl) + 1];
        ((float4*)(item_s + bl * 68))[c4] =
            *(const float4*)(entity_emb + (size_t)ei * DD + c4 * 4);
    }
    __syncthreads();

    // each thread: j-chunk j4..j4+3 for b-locals bl0 and bl0+16
    const int j4  = (tid & 15) * 4;
    const int bl0 = tid >> 4;               // 0..15
    float4 acc0 = {0.f, 0.f, 0.f, 0.f};
    float4 acc1 = {0.f, 0.f, 0.f, 0.f};
    #pragma unroll 8
    for (int i = 0; i < DD; ++i) {
        const float4 rv = *(const float4*)(R_s + i * DD + j4);
        const float a0 = item_s[bl0 * 68 + i];
        const float a1 = item_s[(bl0 + 16) * 68 + i];
        acc0.x += a0 * rv.x; acc0.y += a0 * rv.y;
        acc0.z += a0 * rv.z; acc0.w += a0 * rv.w;
        acc1.x += a1 * rv.x; acc1.y += a1 * rv.y;
        acc1.z += a1 * rv.z; acc1.w += a1 * rv.w;
    }
    size_t q0 = ((size_t)(b0 + bl0) * NREL + r) * DD + j4;
    size_t q1 = ((size_t)(b0 + bl0 + 16) * NREL + r) * DD + j4;
    *(float4*)(qout + q0) = acc0;
    *(float4*)(qout + q1) = acc1;
}

// ---------------- Kernel B: gather h + Q rows, softmax, combine ------------
// Rewritten: q rows never touch LDS (register-resident in the exact layout
// the v-dot needs); v-dot via in-register 16-lane shuffle tree; softmax
// computed redundantly per-wave so p[t] lives at lane t (no p_s round-trip).
// 2 barriers total (was 4-5).  grid = BB, block = 256 (4 waves).
#define HS 65   // odd stride: u-phase stride-1 reads are 2-way (free)

__global__ __launch_bounds__(256, 4) void ripple_apply(
    const int* __restrict__ edge_index,
    const int* __restrict__ ripple_sets,    // (H,B,M,2) int32
    const float* __restrict__ entity_emb,
    const float* __restrict__ qg,           // (B, NREL, D)
    float* __restrict__ out)                // (B,1)
{
    __shared__ float item_s[DD];
    __shared__ float h_s[HH * MM * HS];     // 64 x 65 = 16.6 KB
    __shared__ float v_s[HH * MM];          // 64 scores
    __shared__ float up_s[4 * 68];          // per-wave u partials

    const int b    = blockIdx.x;
    const int tid  = threadIdx.x;
    const int lane = tid & 63;
    const int r0   = tid >> 4;              // 0..15 (row group)
    const int c4   = tid & 15;              // 0..15 (float4 column)

    // ---- Phase 0: all 8 index loads up front (L2-hot, 512 KB table) ----
    int head[4], rel[4];
    #pragma unroll
    for (int k = 0; k < 4; ++k) {
        int row = r0 + 16 * k;              // 0..63
        int hop = row >> 5, m = row & 31;
        size_t ibase = ((size_t)(hop * BB + b) * MM + m) * 2;
        head[k] = ripple_sets[ibase];
        rel[k]  = ripple_sets[ibase + 1];
    }
    if (tid < DD) {
        int item_idx = edge_index[2 * b + 1];       // broadcast, L2-hot
        item_s[tid] = entity_emb[(size_t)item_idx * DD + tid];
    }

    // ---- Phase 1: 8 independent float4 gathers straight to registers ----
    float4 hv[4], qv[4];
    #pragma unroll
    for (int k = 0; k < 4; ++k)
        hv[k] = *(const float4*)(entity_emb + (size_t)head[k] * DD + c4 * 4);
    #pragma unroll
    for (int k = 0; k < 4; ++k)
        qv[k] = *(const float4*)(qg + ((size_t)b * NREL + rel[k]) * DD + c4 * 4);

    // ---- Phase 2: h -> LDS (u-phase needs it) + in-register v partials ----
    float vp[4];
    #pragma unroll
    for (int k = 0; k < 4; ++k) {
        int row = r0 + 16 * k;
        float* hd = h_s + row * HS + c4 * 4;   // scalar stores: HS=65 unaligned
        hd[0] = hv[k].x; hd[1] = hv[k].y; hd[2] = hv[k].z; hd[3] = hv[k].w;
        vp[k] = hv[k].x * qv[k].x + hv[k].y * qv[k].y
              + hv[k].z * qv[k].z + hv[k].w * qv[k].w;
    }
    // reduce the dot over the 16 c4-lanes (lane bits 0..3)
    #pragma unroll
    for (int off = 1; off < 16; off <<= 1) {
        #pragma unroll
        for (int k = 0; k < 4; ++k)
            vp[k] += __shfl_xor(vp[k], off, 64);
    }
    if (c4 == 0) {
        #pragma unroll
        for (int k = 0; k < 4; ++k)
            v_s[r0 + 16 * k] = vp[k];
    }
    __syncthreads();                        // h_s + v_s complete

    // ---- Phase 3: redundant per-wave softmax; lane holds t = lane ----
    // xor offsets <=16 stay inside each 32-lane half (= one hop)
    float v  = v_s[lane];
    float mx = v;
    #pragma unroll
    for (int off = 16; off > 0; off >>= 1)
        mx = fmaxf(mx, __shfl_xor(mx, off, 64));
    float e = expf(v - mx);
    float s = e;
    #pragma unroll
    for (int off = 16; off > 0; off >>= 1)
        s += __shfl_xor(s, off, 64);
    float p = e / s;                        // p[t=lane], in every wave

    // ---- Phase 4: u partials; wave w covers t in [16w, 16w+16) ----
    const int w = tid >> 6;
    float u = 0.f;
    #pragma unroll
    for (int tt = 0; tt < 16; ++tt) {
        int t = w * 16 + tt;
        float pt = __shfl(p, t, 64);        // uniform broadcast from lane t
        u += pt * h_s[t * HS + lane];       // stride-1 across lanes: free
    }
    up_s[w * 68 + lane] = u;
    __syncthreads();

    // ---- Phase 5: combine 4 waves, dot with item, write ----
    if (tid < DD) {
        float uu = up_s[tid] + up_s[68 + tid] + up_s[136 + tid] + up_s[204 + tid];
        float prod = uu * item_s[tid];
        #pragma unroll
        for (int off = 32; off > 0; off >>= 1)
            prod += __shfl_down(prod, off, 64);
        if (tid == 0) out[b] = prod;
    }
}

extern "C" void kernel_launch(void* const* d_in, const int* in_sizes, int n_in,
                              void* d_out, int out_size, void* d_ws, size_t ws_size,
                              hipStream_t stream) {
    const int*   edge_index   = (const int*)d_in[0];
    const int*   ripple_sets  = (const int*)d_in[1];
    const float* entity_emb   = (const float*)d_in[2];
    const float* relation_emb = (const float*)d_in[3];
    float* out = (float*)d_out;
    float* qbuf = (float*)d_ws;             // B*NREL*D floats = 8 MB
    (void)in_sizes; (void)n_in; (void)out_size; (void)ws_size;

    compute_q<<<dim3(BB / TBB, NREL), dim3(256), 0, stream>>>(
        edge_index, entity_emb, relation_emb, qbuf);
    ripple_apply<<<dim3(BB), dim3(256), 0, stream>>>(
        edge_index, ripple_sets, entity_emb, qbuf, out);
}

// Round 2
// 170.156 us; speedup vs baseline: 1.0196x; 1.0196x over previous
//
#include <hip/hip_runtime.h>
#include <math.h>

#define BB   1024
#define MM   32
#define HH   2
#define DD   64
#define NREL 32
#define TBB  32          // b-tile per block in kernel A

// ---------------- Kernel A: Q[b][r][j] = sum_i item[b][i] * R[r][i][j] -----
// grid = (BB/TBB, NREL), block = 256.  ~2 us, near compute floor.
__global__ __launch_bounds__(256) void compute_q(
    const int* __restrict__ edge_index,     // (B,2)
    const float* __restrict__ entity_emb,   // (N_ENT, D)
    const float* __restrict__ relation_emb, // (NREL, D*D)
    float* __restrict__ qout)               // (B, NREL, D)
{
    __shared__ float R_s[DD * DD];          // 16 KB, row-major R[i][j]
    __shared__ float item_s[TBB * 68];      // stride 68: 16B-aligned, banks spread

    const int r   = blockIdx.y;
    const int b0  = blockIdx.x * TBB;
    const int tid = threadIdx.x;

    // stage R_r: 1024 float4, 4 per thread (coalesced)
    const float4* Rg = (const float4*)(relation_emb + (size_t)r * DD * DD);
    #pragma unroll
    for (int k = 0; k < 4; ++k)
        ((float4*)R_s)[tid + 256 * k] = Rg[tid + 256 * k];

    // stage 32 item rows: 512 float4, 2 per thread
    #pragma unroll
    for (int k = 0; k < 2; ++k) {
        int idx = tid + 256 * k;            // 0..511
        int bl  = idx >> 4;                 // 0..31
        int c4  = idx & 15;                 // 0..15
        int ei  = edge_index[2 * (b0 + bl) + 1];
        ((float4*)(item_s + bl * 68))[c4] =
            *(const float4*)(entity_emb + (size_t)ei * DD + c4 * 4);
    }
    __syncthreads();

    // each thread: j-chunk j4..j4+3 for b-locals bl0 and bl0+16
    const int j4  = (tid & 15) * 4;
    const int bl0 = tid >> 4;               // 0..15
    float4 acc0 = {0.f, 0.f, 0.f, 0.f};
    float4 acc1 = {0.f, 0.f, 0.f, 0.f};
    #pragma unroll 8
    for (int i = 0; i < DD; ++i) {
        const float4 rv = *(const float4*)(R_s + i * DD + j4);
        const float a0 = item_s[bl0 * 68 + i];
        const float a1 = item_s[(bl0 + 16) * 68 + i];
        acc0.x += a0 * rv.x; acc0.y += a0 * rv.y;
        acc0.z += a0 * rv.z; acc0.w += a0 * rv.w;
        acc1.x += a1 * rv.x; acc1.y += a1 * rv.y;
        acc1.z += a1 * rv.z; acc1.w += a1 * rv.w;
    }
    size_t q0 = ((size_t)(b0 + bl0) * NREL + r) * DD + j4;
    size_t q1 = ((size_t)(b0 + bl0 + 16) * NREL + r) * DD + j4;
    *(float4*)(qout + q0) = acc0;
    *(float4*)(qout + q1) = acc1;
}

// ---------------- Kernel B: gather h + Q rows, softmax, combine ------------
// grid = BB, block = 256.  All phases use all 256 threads (or 64 lanes
// with shuffle parallelism); indices loaded straight from global (L2-hot).
#define HS 65   // odd stride: (t+j)%32 spreads banks, <=2-way everywhere (free)

__global__ __launch_bounds__(256) void ripple_apply(
    const int* __restrict__ edge_index,
    const int* __restrict__ ripple_sets,    // (H,B,M,2) int32
    const float* __restrict__ entity_emb,
    const float* __restrict__ qg,           // (B, NREL, D)
    float* __restrict__ out)                // (B,1)
{
    __shared__ float item_s[DD];
    __shared__ float h_s[HH * MM * HS];     // 64 x 65
    __shared__ float q_s[HH * MM * HS];     // 64 x 65
    __shared__ float vp_s[4 * 64];          // v partials (quarter-dots)
    __shared__ float p_s[HH * MM];
    __shared__ float up_s[4 * 68];          // u partials

    const int b   = blockIdx.x;
    const int tid = threadIdx.x;

    if (tid < DD) {
        int item_idx = edge_index[2 * b + 1];       // broadcast, L2-hot
        item_s[tid] = entity_emb[(size_t)item_idx * DD + tid];
    }

    // gather h rows and Q rows: 64 rows x 16 float4 each; indices read
    // directly (16 threads share one row -> broadcast load, 512 KB L2-hot)
    #pragma unroll
    for (int k = 0; k < 4; ++k) {
        int idx = tid + 256 * k;            // 0..1023
        int row = idx >> 4;                 // t: 0..63
        int c4  = idx & 15;
        int hop = row >> 5, m = row & 31;
        size_t ibase = ((size_t)(hop * BB + b) * MM + m) * 2;
        int head = ripple_sets[ibase];
        int rel  = ripple_sets[ibase + 1];
        const float4 hv = *(const float4*)(entity_emb + (size_t)head * DD + c4 * 4);
        float* hd = h_s + row * HS + c4 * 4;
        hd[0] = hv.x; hd[1] = hv.y; hd[2] = hv.z; hd[3] = hv.w;
        const float4 qv = *(const float4*)(qg + ((size_t)b * NREL + rel) * DD + c4 * 4);
        float* qd = q_s + row * HS + c4 * 4;
        qd[0] = qv.x; qd[1] = qv.y; qd[2] = qv.z; qd[3] = qv.w;
    }
    __syncthreads();

    // v[t] = dot(Q_row[t], h[t]) -- split 4 ways: wave w does j-chunk w*16
    {
        int t = tid & 63;
        int q = tid >> 6;                   // 0..3
        const float* qp = q_s + t * HS + q * 16;
        const float* hp = h_s + t * HS + q * 16;
        float acc = 0.f;
        #pragma unroll
        for (int j = 0; j < 16; ++j) acc += qp[j] * hp[j];
        vp_s[q * 64 + t] = acc;
    }
    __syncthreads();

    // lane-parallel softmax: lane t holds v[t]; xor-offsets <=16 stay inside
    // each 32-lane half (= one hop)
    if (tid < HH * MM) {
        float v = vp_s[tid] + vp_s[64 + tid] + vp_s[128 + tid] + vp_s[192 + tid];
        float mx = v;
        #pragma unroll
        for (int off = 16; off > 0; off >>= 1)
            mx = fmaxf(mx, __shfl_xor(mx, off, 64));
        float e = expf(v - mx);
        float s = e;
        #pragma unroll
        for (int off = 16; off > 0; off >>= 1)
            s += __shfl_xor(s, off, 64);
        p_s[tid] = e / s;
    }
    __syncthreads();

    // u_d = sum_t p[t]*h[t][d] -- split 4 ways over t (16 t's per wave)
    {
        int d    = tid & 63;
        int part = tid >> 6;                // 0..3
        float u = 0.f;
        #pragma unroll
        for (int tt = 0; tt < 16; ++tt) {
            int t = part * 16 + tt;
            u += p_s[t] * h_s[t * HS + d];  // p_s broadcast; h_s 2-way
        }
        up_s[part * 68 + d] = u;
    }
    __syncthreads();

    if (tid < DD) {
        float u = up_s[tid] + up_s[68 + tid] + up_s[136 + tid] + up_s[204 + tid];
        float prod = u * item_s[tid];
        #pragma unroll
        for (int off = 32; off > 0; off >>= 1) prod += __shfl_down(prod, off, 64);
        if (tid == 0) out[b] = prod;
    }
}

extern "C" void kernel_launch(void* const* d_in, const int* in_sizes, int n_in,
                              void* d_out, int out_size, void* d_ws, size_t ws_size,
                              hipStream_t stream) {
    const int*   edge_index   = (const int*)d_in[0];
    const int*   ripple_sets  = (const int*)d_in[1];
    const float* entity_emb   = (const float*)d_in[2];
    const float* relation_emb = (const float*)d_in[3];
    float* out = (float*)d_out;
    float* qbuf = (float*)d_ws;             // B*NREL*D floats = 8 MB
    (void)in_sizes; (void)n_in; (void)out_size; (void)ws_size;

    compute_q<<<dim3(BB / TBB, NREL), dim3(256), 0, stream>>>(
        edge_index, entity_emb, relation_emb, qbuf);
    ripple_apply<<<dim3(BB), dim3(256), 0, stream>>>(
        edge_index, ripple_sets, entity_emb, qbuf, out);
}